// Round 6
// baseline (317.678 us; speedup 1.0000x reference)
//
#include <hip/hip_runtime.h>
#include <hip/hip_cooperative_groups.h>
#include <math.h>

namespace cg = cooperative_groups;

#define D 128
#define C 64
#define NTHREADS 256
#define MAXGRID 512   // 2 blocks/CU (35 KB LDS each) -> co-resident on 256 CUs

// Monotone float->uint key: preserves order under unsigned max.
// key(x) > 0 for any finite float x, so 0 == "empty".
__device__ __forceinline__ unsigned f2key(float f) {
  unsigned u = __float_as_uint(f);
  return (u & 0x80000000u) ? ~u : (u | 0x80000000u);
}
__device__ __forceinline__ float key2f(unsigned k) {
  unsigned u = (k & 0x80000000u) ? (k & 0x7fffffffu) : ~k;
  return __uint_as_float(u);
}

// Single cooperative kernel:
//  Phase A: per-block LDS segment-max (fire-and-forget ds_max_u32, swizzled
//           2-way/bank), coalesced partial write (R4 showed global atomics
//           into 512 lines cost +19us -> keep the partial round-trip).
//  grid.sync()
//  Phase B: merge nb partials -> core_embs. 32 outputs/block (128B-contiguous
//           wave reads), 8 readers/output, unroll-8 -> ~2MB in flight, BW-bound.
//  grid.sync()
//  Phase C: out = relu(CE@Wself + (con@CE)@Wmsg + b), 2 rows/block.
__global__ __launch_bounds__(NTHREADS) void fused_all(
    const int* __restrict__ assign, const float* __restrict__ qe,
    unsigned* __restrict__ part, float* __restrict__ core_embs,
    const float* __restrict__ padding, const float* __restrict__ con,
    const float* __restrict__ Wself, const float* __restrict__ Wmsg,
    const float* __restrict__ bias, float* __restrict__ out,
    int Q, int niter, int nb) {
  __shared__ unsigned buf[C * D];  // 32 KB; reused as CE (float) in phase C
  __shared__ unsigned red[NTHREADS];
  __shared__ float MrowS[2][D];
  __shared__ float crowS[2][C];
  int tid = threadIdx.x;

  // ---------------- Phase A: segment max into LDS, then partial write ------
  for (int i = tid; i < C * D; i += NTHREADS) buf[i] = 0u;
  __syncthreads();

  int lane = tid & 31;  // dim quad: dims [lane*4, lane*4+4)
  int r = tid >> 5;     // row slot 0..7

  for (int it = blockIdx.x; it < niter; it += gridDim.x) {
    int base = it * 32;
    if (base + 32 <= Q) {
      float4 v[4];
      int a[4];
#pragma unroll
      for (int i = 0; i < 4; ++i) {
        int row = base + i * 8 + r;
        v[i] = *(const float4*)&qe[(size_t)row * D + lane * 4];
        a[i] = assign[row] * D + lane;
      }
#pragma unroll
      for (int i = 0; i < 4; ++i) {
        atomicMax(&buf[a[i] +  0], f2key(v[i].x));
        atomicMax(&buf[a[i] + 32], f2key(v[i].y));
        atomicMax(&buf[a[i] + 64], f2key(v[i].z));
        atomicMax(&buf[a[i] + 96], f2key(v[i].w));
      }
    } else {
      for (int i = 0; i < 4; ++i) {
        int row = base + i * 8 + r;
        if (row < Q) {
          float4 v = *(const float4*)&qe[(size_t)row * D + lane * 4];
          int a = assign[row] * D + lane;
          atomicMax(&buf[a +  0], f2key(v.x));
          atomicMax(&buf[a + 32], f2key(v.y));
          atomicMax(&buf[a + 64], f2key(v.z));
          atomicMax(&buf[a + 96], f2key(v.w));
        }
      }
    }
  }
  __syncthreads();

  // Un-swizzle, coalesced partial store.
  {
    unsigned* outp = part + (size_t)blockIdx.x * (C * D);
    for (int i = tid; i < C * D; i += NTHREADS) {
      int d = i & 127;
      outp[i] = buf[(i & ~127) + (d & 3) * 32 + (d >> 2)];
    }
  }

  cg::this_grid().sync();

  // ---------------- Phase B: merge partials -> core_embs -------------------
  for (int ob = blockIdx.x * 32; ob < C * D; ob += gridDim.x * 32) {
    int o = ob + (tid & 31);
    int rdr = tid >> 5;  // 0..7
    unsigned m = 0u;
#pragma unroll 8
    for (int br = rdr; br < nb; br += 8)
      m = max(m, part[(size_t)br * (C * D) + o]);
    red[tid] = m;
    __syncthreads();
    if (tid < 32) {
      unsigned k = m;  // rdr==0 contribution already in m
#pragma unroll
      for (int j = 1; j < 8; ++j) k = max(k, red[j * 32 + tid]);
      core_embs[o] = k ? key2f(k) : padding[o & (D - 1)];
    }
    __syncthreads();
  }

  cg::this_grid().sync();

  // ---------------- Phase C: fused GNN GEMMs, 2 rows per block -------------
  float* CE = (float*)buf;
  int half = tid >> 7;   // 0/1 -> output row within block
  int t = tid & 127;
  // CE staged once (same for all rows).
  for (int i = tid; i < C * D; i += NTHREADS) CE[i] = core_embs[i];

  for (int c = blockIdx.x * 2 + half; c < C; c += gridDim.x * 2) {
    if (t < C) crowS[half][t] = con[c * C + t];
    __syncthreads();
    float m = 0.f;
#pragma unroll 8
    for (int j = 0; j < C; ++j) m += crowS[half][j] * CE[j * D + t];
    MrowS[half][t] = m;
    __syncthreads();
    float acc = bias[t];
#pragma unroll 8
    for (int k = 0; k < D; ++k) acc += CE[c * D + k] * Wself[k * D + t];
#pragma unroll 8
    for (int k = 0; k < D; ++k) acc += MrowS[half][k] * Wmsg[k * D + t];
    out[c * D + t] = fmaxf(acc, 0.f);
  }
}

extern "C" void kernel_launch(void* const* d_in, const int* in_sizes, int n_in,
                              void* d_out, int out_size, void* d_ws, size_t ws_size,
                              hipStream_t stream) {
  const int* assign    = (const int*)d_in[0];
  const float* qe      = (const float*)d_in[1];
  const float* padding = (const float*)d_in[2];
  const float* con     = (const float*)d_in[3];
  const float* Wself   = (const float*)d_in[4];
  const float* Wmsg    = (const float*)d_in[5];
  const float* bias    = (const float*)d_in[6];
  float* out = (float*)d_out;
  int Q = in_sizes[0];

  const size_t slot = (size_t)C * D;  // 8192 elems = 32 KB
  size_t avail = ws_size / 4;
  long nb_max = (long)((avail > slot ? avail - slot : slot) / slot);
  int nb = (int)(nb_max < MAXGRID ? nb_max : MAXGRID);
  if (nb < 1) nb = 1;

  unsigned* part   = (unsigned*)d_ws;
  float* core_embs = (float*)((unsigned*)d_ws + (size_t)nb * slot);

  int niter = (Q + 31) / 32;

  void* args[] = {
    (void*)&assign, (void*)&qe, (void*)&part, (void*)&core_embs,
    (void*)&padding, (void*)&con, (void*)&Wself, (void*)&Wmsg,
    (void*)&bias, (void*)&out, (void*)&Q, (void*)&niter, (void*)&nb,
  };
  hipLaunchCooperativeKernel((void*)fused_all, dim3(nb), dim3(NTHREADS),
                             args, 0, stream);
}

// Round 7
// 182.364 us; speedup vs baseline: 1.7420x; 1.7420x over previous
//
#include <hip/hip_runtime.h>
#include <math.h>

#define D 128
#define C 64
#define P1_THREADS 1024  // 16 waves/CU at 1 block/CU -> 50% occupancy
#define P1_GRID 256      // nb=256 partial buffers: halves partial traffic vs 512

// Monotone float->uint key: preserves order under unsigned max.
// key(x) > 0 for any finite float x, so 0 == "empty".
__device__ __forceinline__ unsigned f2key(float f) {
  unsigned u = __float_as_uint(f);
  return (u & 0x80000000u) ? ~u : (u | 0x80000000u);
}
__device__ __forceinline__ float key2f(unsigned k) {
  unsigned u = (k & 0x80000000u) ? (k & 0x7fffffffu) : ~k;
  return __uint_as_float(u);
}

// Phase 1: per-block segment max via fire-and-forget LDS atomicMax (ds_max_u32,
// no RMW chain). 1024 threads/block, tile = 128 rows, 4 float4 loads in
// flight per thread. LDS swizzle: idx = core*128 + (d%4)*32 + d/4 -> ds_max
// is 2-way/bank (free). Coalesced partial write (R4: global atomics into 512
// lines cost +19us; R6: cooperative fusion cost +131us -- keep this shape).
__global__ __launch_bounds__(P1_THREADS) void p1_segmax(
    const int* __restrict__ assign, const float* __restrict__ qe,
    unsigned* __restrict__ part, int Q, int niter) {
  __shared__ unsigned buf[C * D];  // 32 KB
  int tid = threadIdx.x;
  for (int i = tid; i < C * D; i += P1_THREADS) buf[i] = 0u;
  __syncthreads();

  int lane = tid & 31;  // dim quad: dims [lane*4, lane*4+4)
  int r = tid >> 5;     // row slot 0..31

  for (int it = blockIdx.x; it < niter; it += gridDim.x) {
    int base = it * 128;
    if (base + 128 <= Q) {
      float4 v[4];
      int a[4];
#pragma unroll
      for (int i = 0; i < 4; ++i) {
        int row = base + i * 32 + r;
        v[i] = *(const float4*)&qe[(size_t)row * D + lane * 4];
        a[i] = assign[row] * D + lane;
      }
#pragma unroll
      for (int i = 0; i < 4; ++i) {
        atomicMax(&buf[a[i] +  0], f2key(v[i].x));
        atomicMax(&buf[a[i] + 32], f2key(v[i].y));
        atomicMax(&buf[a[i] + 64], f2key(v[i].z));
        atomicMax(&buf[a[i] + 96], f2key(v[i].w));
      }
    } else {
      for (int i = 0; i < 4; ++i) {
        int row = base + i * 32 + r;
        if (row < Q) {
          float4 v = *(const float4*)&qe[(size_t)row * D + lane * 4];
          int a = assign[row] * D + lane;
          atomicMax(&buf[a +  0], f2key(v.x));
          atomicMax(&buf[a + 32], f2key(v.y));
          atomicMax(&buf[a + 64], f2key(v.z));
          atomicMax(&buf[a + 96], f2key(v.w));
        }
      }
    }
  }
  __syncthreads();

  // Un-swizzle on write-out (coalesced global stores).
  unsigned* outp = part + (size_t)blockIdx.x * (C * D);
  for (int i = tid; i < C * D; i += P1_THREADS) {
    int d = i & 127;
    outp[i] = buf[(i & ~127) + (d & 3) * 32 + (d >> 2)];
  }
}

// Phase 2: reduce nb partial key-buffers -> core_embs floats (padding applied).
// 256 blocks x 32 consecutive outputs (128B-contiguous per half-wave) x 8
// readers, unroll-8 -> ~2 MB in flight device-wide.
__global__ __launch_bounds__(256) void p2_merge(
    const unsigned* __restrict__ part, const float* __restrict__ padding,
    float* __restrict__ core_embs, int nb) {
  __shared__ unsigned red[256];
  int tid = threadIdx.x;
  int o = blockIdx.x * 32 + (tid & 31);
  int rdr = tid >> 5;  // 0..7
  unsigned m = 0u;
#pragma unroll 8
  for (int br = rdr; br < nb; br += 8)
    m = max(m, part[(size_t)br * (C * D) + o]);
  red[tid] = m;
  __syncthreads();
  if (tid < 32) {
    unsigned k = m;
#pragma unroll
    for (int j = 1; j < 8; ++j) k = max(k, red[j * 32 + tid]);
    core_embs[o] = k ? key2f(k) : padding[o & (D - 1)];
  }
}

// Phase 3 (fused): out = relu(CE @ Wself + (con @ CE) @ Wmsg + b)
// using con@(CE@Wmsg) == (con@CE)@Wmsg. Full CE (32 KB) staged in LDS.
__global__ __launch_bounds__(D) void p3_fused(
    const float* __restrict__ core_embs, const float* __restrict__ con,
    const float* __restrict__ Wself, const float* __restrict__ Wmsg,
    const float* __restrict__ b, float* __restrict__ out) {
  __shared__ float CE[C * D];  // 32 KB
  __shared__ float Mrow[D];
  __shared__ float crow[C];
  int t = threadIdx.x;
  int c = blockIdx.x;
  for (int i = t; i < C * D; i += D) CE[i] = core_embs[i];
  if (t < C) crow[t] = con[c * C + t];
  __syncthreads();
  // Mrow[t] = con[c] . CE[:, t]
  float m = 0.f;
#pragma unroll 8
  for (int j = 0; j < C; ++j) m += crow[j] * CE[j * D + t];
  Mrow[t] = m;
  __syncthreads();
  float acc = b[t];
#pragma unroll 8
  for (int k = 0; k < D; ++k) acc += CE[c * D + k] * Wself[k * D + t];
#pragma unroll 8
  for (int k = 0; k < D; ++k) acc += Mrow[k] * Wmsg[k * D + t];
  out[c * D + t] = fmaxf(acc, 0.f);
}

extern "C" void kernel_launch(void* const* d_in, const int* in_sizes, int n_in,
                              void* d_out, int out_size, void* d_ws, size_t ws_size,
                              hipStream_t stream) {
  const int* assign    = (const int*)d_in[0];
  const float* qe      = (const float*)d_in[1];
  const float* padding = (const float*)d_in[2];
  const float* con     = (const float*)d_in[3];
  const float* Wself   = (const float*)d_in[4];
  const float* Wmsg    = (const float*)d_in[5];
  const float* b       = (const float*)d_in[6];
  float* out = (float*)d_out;
  int Q = in_sizes[0];

  const size_t slot = (size_t)C * D;  // 8192 elems = 32 KB
  size_t avail = ws_size / 4;
  long nb_max = (long)((avail > slot ? avail - slot : slot) / slot);
  int nb = (int)(nb_max < P1_GRID ? nb_max : P1_GRID);
  if (nb < 1) nb = 1;

  unsigned* part   = (unsigned*)d_ws;
  float* core_embs = (float*)((unsigned*)d_ws + (size_t)nb * slot);

  int niter = (Q + 127) / 128;

  hipLaunchKernelGGL(p1_segmax, dim3(nb), dim3(P1_THREADS), 0, stream,
                     assign, qe, part, Q, niter);
  hipLaunchKernelGGL(p2_merge, dim3((C * D) / 32), dim3(256), 0, stream,
                     part, padding, core_embs, nb);
  hipLaunchKernelGGL(p3_fused, dim3(C), dim3(D), 0, stream,
                     core_embs, con, Wself, Wmsg, b, out);
}